// Round 1
// baseline (1711.902 us; speedup 1.0000x reference)
//
#include <hip/hip_runtime.h>
#include <math.h>

// Problem constants (LSTMModel_39221641347102)
constexpr int kT = 512;   // sequence length
constexpr int kH = 16;    // hidden size
constexpr int kL = 8;     // layers
constexpr int kG = 64;    // 4*kH gates

// One block per batch element. 8 waves (512 threads); wave l = layer l.
// Lane g (0..63) owns gate g of its layer: z[g] = b[g] + Wih[g,:].v + Whh[g,:].h
// Pipeline over global step s: wave l processes t = s - l. LDS handoff slots.
__global__ __launch_bounds__(512, 4)
void lstm_fused(const float* __restrict__ x,
                const float* __restrict__ Wih,
                const float* __restrict__ Whh,
                const float* __restrict__ bih,
                const float* __restrict__ bhh,
                const float* __restrict__ Wp, const float* __restrict__ bp,
                const float* __restrict__ Wo, const float* __restrict__ bo,
                float* __restrict__ out)
{
    const int b    = blockIdx.x;
    const int tid  = threadIdx.x;
    const int l    = tid >> 6;    // wave index = layer
    const int lane = tid & 63;    // gate index
    const int j    = lane & 15;   // hidden unit index within gate group

    // vbuf[l] = input vector to layer l at the current step (x for l==0, h_{l-1} else)
    __shared__ __align__(16) float vbuf[(kL + 1) * kH];
    // hown[l] = layer l's own h(t-1)
    __shared__ __align__(16) float hown[kL * kH];

    // --- load weights: row `lane` of [Wih_l | Whh_l] into registers ---
    float wi[kH], wh[kH];
    const float* wih_row = Wih + (size_t)(l * kG + lane) * kH;
    const float* whh_row = Whh + (size_t)(l * kG + lane) * kH;
    #pragma unroll
    for (int k = 0; k < kH; k += 4) {
        float4 a = *(const float4*)(wih_row + k);
        wi[k] = a.x; wi[k+1] = a.y; wi[k+2] = a.z; wi[k+3] = a.w;
        float4 c4 = *(const float4*)(whh_row + k);
        wh[k] = c4.x; wh[k+1] = c4.y; wh[k+2] = c4.z; wh[k+3] = c4.w;
    }
    const float bias = bih[l * kG + lane] + bhh[l * kG + lane];

    // --- init LDS: prime x(0) into slot 0, zero own-h ---
    if (l == 0 && lane < kH) {
        vbuf[lane] = x[((size_t)b * kT + 0) * kH + lane];
    }
    if (lane < kH) hown[l * kH + lane] = 0.0f;
    float c = 0.0f, h = 0.0f;

    __syncthreads();

    const float* vin = vbuf + l * kH;
    const float* hin = hown + l * kH;
    // activation selector: gates 32..47 are tanh (m=2), rest sigmoid (m=1)
    const float m = (lane >= 32 && lane < 48) ? 2.0f : 1.0f;

    for (int s = 0; s < kT + kL - 1; ++s) {
        const int t = s - l;
        const bool active = (t >= 0) && (t < kT);

        if (active) {
            // ---- phase A: gate pre-activation (uniform-address LDS reads = broadcast) ----
            float z0 = bias, z1 = 0.f, z2 = 0.f, z3 = 0.f;
            #pragma unroll
            for (int k = 0; k < kH; k += 4) {
                float4 v = *(const float4*)(vin + k);
                z0 += wi[k]   * v.x;
                z1 += wi[k+1] * v.y;
                z2 += wi[k+2] * v.z;
                z3 += wi[k+3] * v.w;
            }
            #pragma unroll
            for (int k = 0; k < kH; k += 4) {
                float4 v = *(const float4*)(hin + k);
                z0 += wh[k]   * v.x;
                z1 += wh[k+1] * v.y;
                z2 += wh[k+2] * v.z;
                z3 += wh[k+3] * v.w;
            }
            const float z = (z0 + z1) + (z2 + z3);

            // unified activation: m=1 -> sigmoid(z); m=2 -> tanh(z)
            const float a = m / (1.0f + __expf(-m * z)) - (m - 1.0f);

            // regroup i/f/g/o via wave64 shuffles
            const float ai = __shfl(a, j);
            const float af = __shfl(a, j + 16);
            const float ag = __shfl(a, j + 32);
            const float ao = __shfl(a, j + 48);

            c = af * c + ai * ag;
            const float tc = 2.0f / (1.0f + __expf(-2.0f * c)) - 1.0f;  // tanh(c)
            h = ao * tc;
        }

        __syncthreads();   // all phase-A reads done

        // ---- phase B: publish h; wave 0 stages next x ----
        if (active && lane < kH) {
            hown[l * kH + lane]       = h;
            vbuf[(l + 1) * kH + lane] = h;   // slot kL write (l==7) is unused, harmless
        }
        if (l == 0 && lane < kH && (s + 1) < kT) {
            vbuf[lane] = x[((size_t)b * kT + (s + 1)) * kH + lane];
        }

        __syncthreads();   // writes visible for next step
    }

    // ---- head: wave 7, lanes 0..5. h(T-1) of layer 7 is in hown[7]. ----
    if (l == kL - 1 && lane < 6) {
        const float* hl = hown + (kL - 1) * kH;
        const bool isPos = (lane < 3);
        const int  r     = isPos ? lane : lane - 3;
        const float* wrow = isPos ? (Wp + r * kH) : (Wo + r * kH);
        float acc = isPos ? bp[r] : bo[r];
        #pragma unroll
        for (int k = 0; k < kH; ++k) acc += wrow[k] * hl[k];
        if (!isPos) acc = 2.0f / (1.0f + __expf(-2.0f * acc)) - 1.0f;  // tanh
        out[(size_t)b * 6 + lane] = acc;
    }
}

extern "C" void kernel_launch(void* const* d_in, const int* in_sizes, int n_in,
                              void* d_out, int out_size, void* d_ws, size_t ws_size,
                              hipStream_t stream) {
    const float* x   = (const float*)d_in[0];
    const float* Wih = (const float*)d_in[1];
    const float* Whh = (const float*)d_in[2];
    const float* bih = (const float*)d_in[3];
    const float* bhh = (const float*)d_in[4];
    const float* Wp  = (const float*)d_in[5];
    const float* bp  = (const float*)d_in[6];
    const float* Wo  = (const float*)d_in[7];
    const float* bo  = (const float*)d_in[8];
    float* out = (float*)d_out;

    const int B = in_sizes[0] / (kT * kH);   // 2048
    lstm_fused<<<dim3(B), dim3(512), 0, stream>>>(x, Wih, Whh, bih, bhh,
                                                  Wp, bp, Wo, bo, out);
}

// Round 2
// 1132.663 us; speedup vs baseline: 1.5114x; 1.5114x over previous
//
#include <hip/hip_runtime.h>
#include <math.h>

// Problem constants (LSTMModel_39221641347102)
constexpr int kT = 512;   // sequence length
constexpr int kH = 16;    // hidden size
constexpr int kL = 8;     // layers
constexpr int kG = 64;    // 4*kH gates

__device__ __forceinline__ float rl(float v, int lane) {
    // wave-uniform lane index -> v_readlane_b32 (SGPR result, free broadcast)
    return __int_as_float(__builtin_amdgcn_readlane(__float_as_int(v), lane));
}

// One block per batch element. 8 waves; wave l = layer l, lane = gate.
// Single barrier per step; parity-double-buffered LDS handoff; weights pinned
// in VGPRs; own-h broadcast via readlane; x prefetched 2 steps ahead.
__global__ __launch_bounds__(512, 4)
void lstm_fused(const float* __restrict__ x,
                const float* __restrict__ Wih,
                const float* __restrict__ Whh,
                const float* __restrict__ bih,
                const float* __restrict__ bhh,
                const float* __restrict__ Wp, const float* __restrict__ bp,
                const float* __restrict__ Wo, const float* __restrict__ bo,
                float* __restrict__ out)
{
    const int b    = blockIdx.x;
    const int tid  = threadIdx.x;
    const int l    = tid >> 6;
    const int lane = tid & 63;
    const int j    = lane & 15;

    // hpub[p][l] = h published by layer l at steps with parity p (for layer l+1)
    __shared__ __align__(16) float hpub[2][kL][kH];
    // xslot[p] = x(t) staged for wave 0, parity p
    __shared__ __align__(16) float xslot[2][kH];

    // ---- load weights: row `lane` of [Wih_l | Whh_l] ----
    float wi[kH], wh[kH];
    {
        const float* wr = Wih + (size_t)(l * kG + lane) * kH;
        const float* hr = Whh + (size_t)(l * kG + lane) * kH;
        #pragma unroll
        for (int k = 0; k < kH; k += 4) {
            float4 a4 = *(const float4*)(wr + k);
            wi[k] = a4.x; wi[k+1] = a4.y; wi[k+2] = a4.z; wi[k+3] = a4.w;
            float4 b4 = *(const float4*)(hr + k);
            wh[k] = b4.x; wh[k+1] = b4.y; wh[k+2] = b4.z; wh[k+3] = b4.w;
        }
    }
    float bias = bih[l * kG + lane] + bhh[l * kG + lane];
    // Pin weights into VGPRs: block rematerialization/sinking of the loads.
    #pragma unroll
    for (int k = 0; k < kH; ++k) {
        asm volatile("" : "+v"(wi[k]), "+v"(wh[k]));
    }
    asm volatile("" : "+v"(bias));

    constexpr float LOG2E = 1.4426950408889634f;
    const bool  tg  = (lane >= 32) && (lane < 48);   // tanh gates (g)
    const float am  = tg ? 2.0f : 1.0f;              // act = am/(1+2^(ank*z)) + ams
    const float ank = -am * LOG2E;
    const float ams = tg ? -1.0f : 0.0f;             // -(m-1)

    // zero the handoff buffers (read during pipeline warm-up)
    if (tid < 2 * kL * kH) ((float*)hpub)[tid] = 0.0f;   // 256 floats

    // x staging init: xslot[1] = x(0); xg holds x(1)
    float xg = 0.0f;
    const float* xb = x + (size_t)b * kT * kH;
    if (l == 0 && lane < kH) {
        xslot[1][lane] = xb[lane];
        xg             = xb[kH + lane];
    }

    float c = 0.0f, h = 0.0f;
    __syncthreads();

    const float* vin0 = (l == 0) ? &xslot[0][0] : &hpub[0][l - 1][0];
    const float* vin1 = (l == 0) ? &xslot[1][0] : &hpub[1][l - 1][0];

    for (int s = 0; s < kT + kL - 1; ++s) {
        const int  t      = s - l;
        const bool active = (t >= 0) & (t < kT);     // wave-uniform

        // ---- input dot: v from LDS (broadcast b128 reads) ----
        const float* vin = ((s + 1) & 1) ? vin1 : vin0;
        float z0 = bias, z1 = 0.f, z2 = 0.f, z3 = 0.f;
        #pragma unroll
        for (int k = 0; k < kH; k += 4) {
            float4 v4 = *(const float4*)(vin + k);
            z0 = fmaf(wi[k],   v4.x, z0);
            z1 = fmaf(wi[k+1], v4.y, z1);
            z2 = fmaf(wi[k+2], v4.z, z2);
            z3 = fmaf(wi[k+3], v4.w, z3);
        }
        // ---- recurrent dot: own h via readlane (no LDS) ----
        #pragma unroll
        for (int k = 0; k < kH; k += 4) {
            z0 = fmaf(wh[k],   rl(h, k),     z0);
            z1 = fmaf(wh[k+1], rl(h, k + 1), z1);
            z2 = fmaf(wh[k+2], rl(h, k + 2), z2);
            z3 = fmaf(wh[k+3], rl(h, k + 3), z3);
        }
        const float z = (z0 + z1) + (z2 + z3);

        // unified sigmoid/tanh: am/(1+2^(ank*z)) + ams
        const float e = __builtin_amdgcn_exp2f(ank * z);
        const float a = fmaf(am, __builtin_amdgcn_rcpf(1.0f + e), ams);

        // gather i,f,g,o for unit j
        const float ai = __shfl(a, j);
        const float af = __shfl(a, j + 16);
        const float ag = __shfl(a, j + 32);
        const float ao = __shfl(a, j + 48);

        const float cn = fmaf(af, c, ai * ag);
        const float e2 = __builtin_amdgcn_exp2f(cn * (-2.0f * LOG2E));
        const float tc = fmaf(2.0f, __builtin_amdgcn_rcpf(1.0f + e2), -1.0f);
        const float hn = ao * tc;
        c = active ? cn : 0.0f;
        h = active ? hn : 0.0f;

        // ---- publish (h is already 0 when inactive -> unconditional) ----
        if (lane < kH) {
            if (l < kL - 1) hpub[s & 1][l][lane] = h;
            if (l == 0) {
                xslot[s & 1][lane] = xg;             // x(s+1) for step s+1
                int tn = s + 2; if (tn > kT - 1) tn = kT - 1;
                xg = xb[(size_t)tn * kH + lane];     // prefetch x(s+2)
            }
        }
        __syncthreads();
    }

    // ---- head: layer-7 h(T-1) lives in wave 7's registers ----
    if (l == kL - 1 && lane < kH) hpub[0][0][lane] = h;
    __syncthreads();
    if (l == kL - 1 && lane < 6) {
        const float* hl   = &hpub[0][0][0];
        const bool  isPos = (lane < 3);
        const int   r     = isPos ? lane : lane - 3;
        const float* wrow = isPos ? (Wp + r * kH) : (Wo + r * kH);
        float acc = isPos ? bp[r] : bo[r];
        #pragma unroll
        for (int k = 0; k < kH; ++k) acc = fmaf(wrow[k], hl[k], acc);
        if (!isPos) {
            const float e3 = __builtin_amdgcn_exp2f(acc * (-2.0f * LOG2E));
            acc = fmaf(2.0f, __builtin_amdgcn_rcpf(1.0f + e3), -1.0f);
        }
        out[(size_t)b * 6 + lane] = acc;
    }
}

extern "C" void kernel_launch(void* const* d_in, const int* in_sizes, int n_in,
                              void* d_out, int out_size, void* d_ws, size_t ws_size,
                              hipStream_t stream) {
    const float* x   = (const float*)d_in[0];
    const float* Wih = (const float*)d_in[1];
    const float* Whh = (const float*)d_in[2];
    const float* bih = (const float*)d_in[3];
    const float* bhh = (const float*)d_in[4];
    const float* Wp  = (const float*)d_in[5];
    const float* bp  = (const float*)d_in[6];
    const float* Wo  = (const float*)d_in[7];
    const float* bo  = (const float*)d_in[8];
    float* out = (float*)d_out;

    const int B = in_sizes[0] / (kT * kH);   // 2048
    lstm_fused<<<dim3(B), dim3(512), 0, stream>>>(x, Wih, Whh, bih, bhh,
                                                  Wp, bp, Wo, bo, out);
}

// Round 3
// 411.704 us; speedup vs baseline: 4.1581x; 2.7512x over previous
//
#include <hip/hip_runtime.h>
#include <math.h>

typedef _Float16 f16x8 __attribute__((ext_vector_type(8)));
typedef _Float16 f16x4 __attribute__((ext_vector_type(4)));
typedef float    f32x4 __attribute__((ext_vector_type(4)));

constexpr int kT  = 512;  // sequence length
constexpr int kH  = 16;   // hidden
constexpr int kL  = 8;    // layers
constexpr int kG  = 64;   // gates = 4*kH
constexpr int kNB = 8;    // real batch columns per block (cols 8-15 run zero-input)
constexpr int kPad = 24;  // f16 row stride (48 B = 3x16 B: b128-aligned, <=2-way banks)

constexpr float kLog2e = 1.4426950408889634f;

__device__ __forceinline__ float sigm2(float z2) {
    // 1/(1+2^z2)
    return __builtin_amdgcn_rcpf(1.0f + __builtin_amdgcn_exp2f(z2));
}

// Block = 8 batch columns, 8 waves; wave l = layer l (wavefront pipeline over t).
// Per step per wave: Z[64x16] = W[64x32] @ [v;h][32x16] via 4x mfma_f32_16x16x32_f16.
// D layout (col=batch=lane&15, row=unit=q*4+reg) => i/f/g/o for one (unit,batch)
// land in the SAME lane => c/h update fully in-lane, no shuffles.
__global__ __launch_bounds__(512, 2)
void lstm_mfma(const float* __restrict__ x,
               const float* __restrict__ Wih, const float* __restrict__ Whh,
               const float* __restrict__ bih, const float* __restrict__ bhh,
               const float* __restrict__ Wp,  const float* __restrict__ bpos,
               const float* __restrict__ Wo,  const float* __restrict__ bori,
               float* __restrict__ out)
{
    const int tid  = threadIdx.x;
    const int l    = tid >> 6;    // wave = layer
    const int lane = tid & 63;
    const int n    = lane & 15;   // batch col (B/D) and A-row m
    const int q    = lane >> 4;   // lane quad

    // h handoff: [parity][layer][batch col][unit(padded)]
    __shared__ __align__(16) _Float16 hbuf[2][kL][16][kPad];
    __shared__ __align__(16) _Float16 xbuf[2][16][kPad];

    // zero-init LDS (rows 8-15 stay zero => clean zero-input columns)
    {
        int* hz = (int*)&hbuf[0][0][0][0];
        for (int i = tid; i < (int)(sizeof(hbuf) / 4); i += 512) hz[i] = 0;
        int* xz = (int*)&xbuf[0][0][0];
        for (int i = tid; i < (int)(sizeof(xbuf) / 4); i += 512) xz[i] = 0;
    }

    // ---- A fragments: A[m=lane&15][k=q*8+j]; k<16 -> Wih, k>=16 -> Whh ----
    f16x8 A[4];
    {
        const float* base = (q < 2) ? (Wih + (size_t)l * kG * kH)
                                    : (Whh + (size_t)l * kG * kH);
        #pragma unroll
        for (int T = 0; T < 4; ++T) {
            const float* src = base + (T * 16 + n) * kH + (q & 1) * 8;
            f16x8 a;
            #pragma unroll
            for (int j = 0; j < 8; ++j) a[j] = (_Float16)src[j];
            A[T] = a;
        }
    }

    // ---- bias folded into activation: act = f(ank*z + ank*bias) ----
    float abk[4][4];   // [tile][reg], D-row unit = q*4+reg
    #pragma unroll
    for (int T = 0; T < 4; ++T) {
        const float ank = (T == 2) ? (-2.0f * kLog2e) : (-kLog2e);
        #pragma unroll
        for (int r = 0; r < 4; ++r) {
            const int g = l * kG + T * 16 + q * 4 + r;
            abk[T][r] = ank * (bih[g] + bhh[g]);
        }
    }

    // ---- B read pointers per parity: lane reads buf[n][q*8 .. q*8+7] ----
    // lane quads 0,1: k=0..15 = v (prev layer h, or x for l==0)
    // lane quads 2,3: k=16..31 = own h
    const _Float16* vb0 = (l == 0) ? &xbuf[0][0][0] : &hbuf[0][l - 1][0][0];
    const _Float16* vb1 = (l == 0) ? &xbuf[1][0][0] : &hbuf[1][l - 1][0][0];
    const int boff = n * kPad + (q & 1) * 8;
    const _Float16* bp0 = ((q < 2) ? vb0 : &hbuf[0][l][0][0]) + boff;
    const _Float16* bp1 = ((q < 2) ? vb1 : &hbuf[1][l][0][0]) + boff;

    // ---- h write pointers (write slot = opposite parity of read slot) ----
    _Float16* hw0 = &hbuf[1][l][n][q * 4];   // even steps (read 0, write 1)
    _Float16* hw1 = &hbuf[0][l][n][q * 4];   // odd steps
    _Float16* xw0 = &xbuf[1][lane >> 3][(lane & 7) * 2];
    _Float16* xw1 = &xbuf[0][lane >> 3][(lane & 7) * 2];

    // ---- x staging (wave 0): lane covers batch=lane>>3, units (lane&7)*2,+1 ----
    const float* xg_ptr =
        x + ((size_t)(blockIdx.x * kNB + (lane >> 3)) * kT) * kH + (lane & 7) * 2;
    float xg0 = 0.f, xg1 = 0.f;
    if (l == 0) {
        float2 v0 = *(const float2*)(xg_ptr);          // x(0) -> slot 0
        xbuf[0][lane >> 3][(lane & 7) * 2]     = (_Float16)v0.x;
        xbuf[0][lane >> 3][(lane & 7) * 2 + 1] = (_Float16)v0.y;
        float2 v1 = *(const float2*)(xg_ptr + kH);     // prefetch x(1)
        xg0 = v1.x; xg1 = v1.y;
    }

    float c[4] = {0.f, 0.f, 0.f, 0.f};
    __syncthreads();

    const f32x4 zeroC = {0.f, 0.f, 0.f, 0.f};

    auto step = [&](int s, const _Float16* bp, _Float16* hw, _Float16* xw) {
        const int  t      = s - l;
        const bool active = ((unsigned)t < (unsigned)kT);   // wave-uniform

        f16x8 B = *(const f16x8*)bp;                        // one ds_read_b128
        f32x4 di = __builtin_amdgcn_mfma_f32_16x16x32_f16(A[0], B, zeroC, 0, 0, 0);
        f32x4 df = __builtin_amdgcn_mfma_f32_16x16x32_f16(A[1], B, zeroC, 0, 0, 0);
        f32x4 dg = __builtin_amdgcn_mfma_f32_16x16x32_f16(A[2], B, zeroC, 0, 0, 0);
        f32x4 dO = __builtin_amdgcn_mfma_f32_16x16x32_f16(A[3], B, zeroC, 0, 0, 0);

        float hh[4];
        #pragma unroll
        for (int r = 0; r < 4; ++r) {
            const float ai = sigm2(fmaf(-kLog2e,        di[r], abk[0][r]));
            const float af = sigm2(fmaf(-kLog2e,        df[r], abk[1][r]));
            const float ag = fmaf(2.0f, sigm2(fmaf(-2.0f * kLog2e, dg[r], abk[2][r])), -1.0f);
            const float ao = sigm2(fmaf(-kLog2e,        dO[r], abk[3][r]));
            float cn = fmaf(af, c[r], ai * ag);
            cn   = active ? cn : 0.0f;
            c[r] = cn;
            const float tc = fmaf(2.0f, sigm2(-2.0f * kLog2e * cn), -1.0f);
            hh[r] = ao * tc;
        }
        if (active) {
            f16x4 hp = { (_Float16)hh[0], (_Float16)hh[1],
                         (_Float16)hh[2], (_Float16)hh[3] };
            *(f16x4*)hw = hp;                               // ds_write_b64
        }
        if (l == 0) {
            xw[0] = (_Float16)xg0;                          // publish x(s+1)
            xw[1] = (_Float16)xg1;
            int tn = s + 2; if (tn > kT - 1) tn = kT - 1;   // prefetch x(s+2)
            float2 v = *(const float2*)(xg_ptr + (size_t)tn * kH);
            xg0 = v.x; xg1 = v.y;
        }
        __syncthreads();                                    // single barrier/step
    };

    for (int s2 = 0; s2 < (kT + kL) / 2; ++s2) {  // 260 double-steps = 520 steps
        step(2 * s2,     bp0, hw0, xw0);
        step(2 * s2 + 1, bp1, hw1, xw1);
    }

    // ---- head: h(T-1) of layer 7 is in hbuf[1][7] (written at s=518) ----
    if (l == kL - 1) {
        const int bb = lane >> 3;       // batch 0..7
        const int r  = lane & 7;        // output 0..5 used
        if (r < 6) {
            const bool  isP  = (r < 3);
            const float* wrow = isP ? (Wp + r * kH) : (Wo + (r - 3) * kH);
            float acc = isP ? bpos[r] : bori[r - 3];
            #pragma unroll
            for (int u = 0; u < kH; ++u)
                acc = fmaf((float)hbuf[1][kL - 1][bb][u], wrow[u], acc);
            if (!isP) acc = fmaf(2.0f, sigm2(-2.0f * kLog2e * acc), -1.0f);
            out[(size_t)(blockIdx.x * kNB + bb) * 6 + r] = acc;
        }
    }
}

extern "C" void kernel_launch(void* const* d_in, const int* in_sizes, int n_in,
                              void* d_out, int out_size, void* d_ws, size_t ws_size,
                              hipStream_t stream) {
    const float* x    = (const float*)d_in[0];
    const float* Wih  = (const float*)d_in[1];
    const float* Whh  = (const float*)d_in[2];
    const float* bih  = (const float*)d_in[3];
    const float* bhh  = (const float*)d_in[4];
    const float* Wp   = (const float*)d_in[5];
    const float* bpos = (const float*)d_in[6];
    const float* Wo   = (const float*)d_in[7];
    const float* bori = (const float*)d_in[8];
    float* out = (float*)d_out;

    const int B = in_sizes[0] / (kT * kH);   // 2048
    lstm_mfma<<<dim3(B / kNB), dim3(512), 0, stream>>>(x, Wih, Whh, bih, bhh,
                                                       Wp, bpos, Wo, bori, out);
}

// Round 4
// 354.200 us; speedup vs baseline: 4.8332x; 1.1624x over previous
//
#include <hip/hip_runtime.h>
#include <math.h>

typedef _Float16 f16x8 __attribute__((ext_vector_type(8)));
typedef _Float16 f16x2 __attribute__((ext_vector_type(2)));
typedef float    f32x4 __attribute__((ext_vector_type(4)));

constexpr int kT   = 512;  // sequence length
constexpr int kH   = 16;   // hidden
constexpr int kL   = 8;    // layers
constexpr int kG   = 64;   // gates = 4*kH
constexpr int kNB  = 8;    // batch columns per block
constexpr int kPad = 24;   // f16 row stride (48 B)
constexpr int kRows= 9;    // 8 batch rows + 1 permanent zero row

constexpr float kL2E = 1.4426950408889634f;

__device__ __forceinline__ float swz8(float v) {
    // lane ^ 8 within 32-lane group (BitMode: xor=8, and=0x1F)
    return __int_as_float(__builtin_amdgcn_ds_swizzle(__float_as_int(v), 0x201F));
}
__device__ __forceinline__ float sigm2(float z) {   // 1/(1+2^z)
    return __builtin_amdgcn_rcpf(1.0f + __builtin_amdgcn_exp2f(z));
}

// Gate-packed MFMA LSTM. Block = 8 batch, 8 waves; wave l = layer l.
// Per step, 2 packed D-tiles via block-diagonal B:
//   P1 = [Wih_i|Wih_f]*[[v,0],[0,v]] + [Whh_i|Whh_f]*[[h,0],[0,h]]
//     -> cols 0-7: i-preact(batch c), cols 8-15: f-preact(batch c-8)
//   P2 same with (g,o). All 16 cols real => activation work halves.
// Cell update split by lane halves: c<8 -> units q*4+{0,1}; c>=8 -> q*4+{2,3}.
__global__ __launch_bounds__(512, 2)
void lstm_gpk(const float* __restrict__ x,
              const float* __restrict__ Wih, const float* __restrict__ Whh,
              const float* __restrict__ bih, const float* __restrict__ bhh,
              const float* __restrict__ Wp,  const float* __restrict__ bpos,
              const float* __restrict__ Wo,  const float* __restrict__ bori,
              float* __restrict__ out)
{
    const int tid  = threadIdx.x;
    const int l    = tid >> 6;
    const int lane = tid & 63;
    const int n    = lane & 15;        // D col
    const int q    = lane >> 4;        // lane quad
    const int bn   = n & 7;            // batch index
    const bool cLow = (n < 8);
    const bool bact = ((q >> 1) == (n >> 3));   // lane holds nonzero B data

    // h per [parity][layer][row][unit]; row 8 stays zero forever
    __shared__ __align__(16) _Float16 hb[2][kL][kRows][kPad];
    __shared__ __align__(16) _Float16 xb[2][kRows][kPad];

    // ---- zero-init LDS ----
    {
        int* hz = (int*)&hb[0][0][0][0];
        for (int i = tid; i < (int)(sizeof(hb) / 4); i += 512) hz[i] = 0;
        int* xz = (int*)&xb[0][0][0];
        for (int i = tid; i < (int)(sizeof(xb) / 4); i += 512) xz[i] = 0;
    }
    __syncthreads();

    // ---- A fragments (A[m=n][k=q*8+j]) ----
    // P1: k<16 -> W_i rows (0-15), k>=16 -> W_f rows (16-31)
    // P2: k<16 -> W_g rows (32-47), k>=16 -> W_o rows (48-63)
    auto loadA = [&](const float* W, int rLow, int rHigh) -> f16x8 {
        const int row = (q < 2) ? (rLow + n) : (rHigh + n);
        const float* src = W + (size_t)l * kG * kH + row * kH + (q & 1) * 8;
        f16x8 a;
        #pragma unroll
        for (int j = 0; j < 8; ++j) a[j] = (_Float16)src[j];
        return a;
    };
    const f16x8 A1P1 = loadA(Wih, 0, 16), A2P1 = loadA(Whh, 0, 16);
    const f16x8 A1P2 = loadA(Wih, 32, 48), A2P2 = loadA(Whh, 32, 48);

    // ---- bias folded into activation arg ----
    float abk1[4], abk2[4];
    const float ank2 = cLow ? (-2.0f * kL2E) : (-kL2E);
    const float am2  = cLow ? 2.0f : 1.0f;
    const float ams2 = cLow ? -1.0f : 0.0f;
    #pragma unroll
    for (int r = 0; r < 4; ++r) {
        const int u  = q * 4 + r;
        const int g1 = l * kG + (cLow ? u : 16 + u);
        const int g2 = l * kG + (cLow ? 32 + u : 48 + u);
        abk1[r] = -kL2E * (bih[g1] + bhh[g1]);
        abk2[r] = ank2  * (bih[g2] + bhh[g2]);
    }

    // ---- B-fragment pointers (per parity); inactive lanes -> zero row 8 ----
    const int roff = (bact ? bn * kPad : 8 * kPad) + (q & 1) * 8;
    const _Float16* b1p[2], * b2p[2];
    #pragma unroll
    for (int p = 0; p < 2; ++p) {
        b1p[p] = ((l == 0) ? &xb[p][0][0] : &hb[p][l - 1][0][0]) + roff;
        b2p[p] = &hb[p][l][0][0] + roff;
    }
    // h write (to parity 1-p): lane writes 2 f16 = units q*4+{0,1} (cLow) or {2,3}
    _Float16* hwp[2];
    #pragma unroll
    for (int p = 0; p < 2; ++p)
        hwp[p] = &hb[1 - p][l][bn][q * 4 + (cLow ? 0 : 2)];
    // x staging write (wave 0): batch lane>>3, units (lane&7)*2
    _Float16* xwp[2];
    #pragma unroll
    for (int p = 0; p < 2; ++p)
        xwp[p] = &xb[1 - p][lane >> 3][(lane & 7) * 2];

    // ---- x(0) stage + x(1) prefetch (wave 0) ----
    const float* xg_ptr =
        x + ((size_t)(blockIdx.x * kNB + (lane >> 3)) * kT) * kH + (lane & 7) * 2;
    float xg0 = 0.f, xg1 = 0.f;
    if (l == 0) {
        float2 v0 = *(const float2*)(xg_ptr);
        xb[0][lane >> 3][(lane & 7) * 2]     = (_Float16)v0.x;
        xb[0][lane >> 3][(lane & 7) * 2 + 1] = (_Float16)v0.y;
        float2 v1 = *(const float2*)(xg_ptr + kH);
        xg0 = v1.x; xg1 = v1.y;
    }

    float c0 = 0.f, c1 = 0.f;   // 2 cell states (split layout)
    __syncthreads();

    const f32x4 zeroC = {0.f, 0.f, 0.f, 0.f};

    auto step = [&](int s, int p) {
        const int  t      = s - l;
        const bool active = ((unsigned)t < (unsigned)kT);   // wave-uniform

        const f16x8 B1 = *(const f16x8*)b1p[p];   // [[v,0],[0,v]]
        const f16x8 B2 = *(const f16x8*)b2p[p];   // [[h,0],[0,h]]

        f32x4 d1 = __builtin_amdgcn_mfma_f32_16x16x32_f16(A2P1, B2, zeroC, 0, 0, 0);
        f32x4 d2 = __builtin_amdgcn_mfma_f32_16x16x32_f16(A2P2, B2, zeroC, 0, 0, 0);
        d1 = __builtin_amdgcn_mfma_f32_16x16x32_f16(A1P1, B1, d1, 0, 0, 0);
        d2 = __builtin_amdgcn_mfma_f32_16x16x32_f16(A1P2, B1, d2, 0, 0, 0);

        // activations: p1s = sigmoid (i|f); p2s = tanh|sigmoid (g|o)
        float p1s[4], p2s[4];
        #pragma unroll
        for (int r = 0; r < 4; ++r)
            p1s[r] = sigm2(fmaf(-kL2E, d1[r], abk1[r]));
        #pragma unroll
        for (int r = 0; r < 4; ++r)
            p2s[r] = fmaf(am2, sigm2(fmaf(ank2, d2[r], abk2[r])), ams2);

        // unpack: co-locate (i,f,g,o) for this lane's 2 (unit,batch) pairs
        float hh[2];
        float cc[2] = {c0, c1};
        #pragma unroll
        for (int k = 0; k < 2; ++k) {
            const float T1 = cLow ? p1s[k + 2] : p1s[k];
            const float R1 = swz8(T1);
            const float iv = cLow ? p1s[k] : R1;
            const float fv = cLow ? R1 : p1s[k + 2];
            const float T2 = cLow ? p2s[k + 2] : p2s[k];
            const float R2 = swz8(T2);
            const float gv = cLow ? p2s[k] : R2;
            const float ov = cLow ? R2 : p2s[k + 2];

            float cn = fmaf(fv, cc[k], iv * gv);
            cn = active ? cn : 0.0f;
            cc[k] = cn;
            const float tc = fmaf(2.0f, sigm2(-2.0f * kL2E * cn), -1.0f);
            hh[k] = ov * tc;
        }
        c0 = cc[0]; c1 = cc[1];

        // publish h (2 f16, b32 write; every lane writes real distinct data)
        f16x2 hp = { (_Float16)hh[0], (_Float16)hh[1] };
        *(f16x2*)hwp[p] = hp;

        if (l == 0) {
            _Float16* xw = xwp[p];
            xw[0] = (_Float16)xg0;
            xw[1] = (_Float16)xg1;
            int tn = s + 2; if (tn > kT - 1) tn = kT - 1;
            float2 v = *(const float2*)(xg_ptr + (size_t)tn * kH);
            xg0 = v.x; xg1 = v.y;
        }
        __syncthreads();
    };

    #pragma unroll 1
    for (int s2 = 0; s2 < (kT + kL) / 2; ++s2) {   // 520 steps (>= 519 needed)
        step(2 * s2,     0);
        step(2 * s2 + 1, 1);
    }

    // ---- head: layer-7 h(T-1) sits in hb[1][7] (written at s=518) ----
    if (l == kL - 1) {
        const int bb = lane >> 3;
        const int r  = lane & 7;
        if (r < 6) {
            const bool  isP   = (r < 3);
            const float* wrow = isP ? (Wp + r * kH) : (Wo + (r - 3) * kH);
            float acc = isP ? bpos[r] : bori[r - 3];
            #pragma unroll
            for (int u = 0; u < kH; ++u)
                acc = fmaf((float)hb[1][kL - 1][bb][u], wrow[u], acc);
            if (!isP) acc = fmaf(2.0f, sigm2(-2.0f * kL2E * acc), -1.0f);
            out[(size_t)(blockIdx.x * kNB + bb) * 6 + r] = acc;
        }
    }
}

extern "C" void kernel_launch(void* const* d_in, const int* in_sizes, int n_in,
                              void* d_out, int out_size, void* d_ws, size_t ws_size,
                              hipStream_t stream) {
    const float* x    = (const float*)d_in[0];
    const float* Wih  = (const float*)d_in[1];
    const float* Whh  = (const float*)d_in[2];
    const float* bih  = (const float*)d_in[3];
    const float* bhh  = (const float*)d_in[4];
    const float* Wp   = (const float*)d_in[5];
    const float* bpos = (const float*)d_in[6];
    const float* Wo   = (const float*)d_in[7];
    const float* bori = (const float*)d_in[8];
    float* out = (float*)d_out;

    const int B = in_sizes[0] / (kT * kH);   // 2048
    lstm_gpk<<<dim3(B / kNB), dim3(512), 0, stream>>>(x, Wih, Whh, bih, bhh,
                                                      Wp, bpos, Wo, bori, out);
}

// Round 5
// 331.009 us; speedup vs baseline: 5.1718x; 1.0701x over previous
//
#include <hip/hip_runtime.h>
#include <math.h>

typedef _Float16 f16x8 __attribute__((ext_vector_type(8)));
typedef _Float16 f16x2 __attribute__((ext_vector_type(2)));
typedef float    f32x4 __attribute__((ext_vector_type(4)));

constexpr int kT    = 512;   // sequence length
constexpr int kH    = 16;    // hidden
constexpr int kL    = 8;     // layers
constexpr int kG    = 64;    // gates
constexpr int kNB   = 8;     // batch per block
constexpr int kPad  = 24;    // f16 row stride (48 B)
constexpr int kRows = 9;     // 8 batch rows + permanent zero row
constexpr int kSlots= 16;    // h ring-buffer depth (skew elasticity ±8)
constexpr int kLyr  = kL + 1;            // lyr 0 = x, lyr 1+l = layer l's h
constexpr int kSE   = kLyr * kRows * kPad;   // f16 elems per slot (1944)
constexpr int kIters= 33;    // 33*16 = 528 steps >= kT+kL-1

constexpr float kL2E = 1.4426950408889634f;

__device__ __forceinline__ float swz8(float v) {   // lane ^ 8 (BitMode)
    return __int_as_float(__builtin_amdgcn_ds_swizzle(__float_as_int(v), 0x201F));
}
__device__ __forceinline__ float sigm2(float z) {  // 1/(1+2^z)
    return __builtin_amdgcn_rcpf(1.0f + __builtin_amdgcn_exp2f(z));
}
__device__ __forceinline__ void cbar() { asm volatile("" ::: "memory"); }

// Barrier-free wavefront-pipelined LSTM. Block = 8 batch, 8 waves = 8 layers.
// Cross-wave sync via per-wave LDS step counters (producer-consumer chain);
// 16-slot h ring buffer gives +-8 steps of skew elasticity. Gate-packed MFMA
// (round-4 math): 4x mfma_f32_16x16x32_f16 per step, i/f and g/o col-packed.
__global__ __launch_bounds__(512, 2)
void lstm_async(const float* __restrict__ x,
                const float* __restrict__ Wih, const float* __restrict__ Whh,
                const float* __restrict__ bih, const float* __restrict__ bhh,
                const float* __restrict__ Wp,  const float* __restrict__ bpos,
                const float* __restrict__ Wo,  const float* __restrict__ bori,
                float* __restrict__ out)
{
    const int tid  = threadIdx.x;
    const int l    = tid >> 6;
    const int lane = tid & 63;
    const int n    = lane & 15;
    const int q    = lane >> 4;
    const int bn   = n & 7;
    const bool cLow = (n < 8);
    const bool bact = ((q >> 1) == (n >> 3));

    // [slot][lyr][row][unit]: lyr 0 = x staging, lyr 1+l = layer l h. 62208 B.
    __shared__ __align__(16) _Float16 hb[kSlots][kLyr][kRows][kPad];
    __shared__ int cnt[kL];              // completed-step counter per wave

    // ---- zero-init LDS; counters to -1 ----
    {
        int* hz = (int*)&hb[0][0][0][0];
        for (int i = tid; i < (int)(sizeof(hb) / 4); i += 512) hz[i] = 0;
        if (tid < kL) cnt[tid] = -1;
    }

    // ---- A fragments (gate-packed, same as round 4) ----
    auto loadA = [&](const float* W, int rLow, int rHigh) -> f16x8 {
        const int row = (q < 2) ? (rLow + n) : (rHigh + n);
        const float* src = W + (size_t)l * kG * kH + row * kH + (q & 1) * 8;
        f16x8 a;
        #pragma unroll
        for (int j = 0; j < 8; ++j) a[j] = (_Float16)src[j];
        return a;
    };
    const f16x8 A1P1 = loadA(Wih, 0, 16), A2P1 = loadA(Whh, 0, 16);
    const f16x8 A1P2 = loadA(Wih, 32, 48), A2P2 = loadA(Whh, 32, 48);

    // ---- bias folded into activation arg ----
    float abk1[4], abk2[4];
    const float ank2 = cLow ? (-2.0f * kL2E) : (-kL2E);
    const float am2  = cLow ? 2.0f : 1.0f;
    const float ams2 = cLow ? -1.0f : 0.0f;
    #pragma unroll
    for (int r = 0; r < 4; ++r) {
        const int u  = q * 4 + r;
        const int g1 = l * kG + (cLow ? u : 16 + u);
        const int g2 = l * kG + (cLow ? 32 + u : 48 + u);
        abk1[r] = -kL2E * (bih[g1] + bhh[g1]);
        abk2[r] = ank2  * (bih[g2] + bhh[g2]);
    }

    // ---- LDS pointers (slot-0 bases; slot k adds k*kSE, folds to ds imm) ----
    const int boff = (bact ? bn * kPad : 8 * kPad) + (q & 1) * 8;
    const _Float16* b1b = &hb[0][l    ][0][0] + boff;   // v-input (x or h_{l-1})
    const _Float16* b2b = &hb[0][l + 1][0][0] + boff;   // own h
    _Float16* hwb = &hb[0][l + 1][bn][q * 4 + (cLow ? 0 : 2)];
    _Float16* xwb = &hb[0][0][lane >> 3][(lane & 7) * 2];

    // ---- x staging (wave 0): prime x(0) -> slot 15, prefetch x(1) ----
    const float* xg_ptr =
        x + ((size_t)(blockIdx.x * kNB + (lane >> 3)) * kT) * kH + (lane & 7) * 2;
    float xg0 = 0.f, xg1 = 0.f;
    if (l == 0) {
        float2 v0 = *(const float2*)(xg_ptr);
        hb[15][0][lane >> 3][(lane & 7) * 2]     = (_Float16)v0.x;
        hb[15][0][lane >> 3][(lane & 7) * 2 + 1] = (_Float16)v0.y;
        float2 v1 = *(const float2*)(xg_ptr + kH);
        xg0 = v1.x; xg1 = v1.y;
    }

    float c0 = 0.f, c1 = 0.f;
    __syncthreads();    // everything above visible; last barrier until the head

    const f32x4 zeroC = {0.f, 0.f, 0.f, 0.f};
    volatile const int* upc = (l > 0)      ? &cnt[l - 1] : nullptr;
    volatile const int* dnc = (l < kL - 1) ? &cnt[l + 1] : nullptr;

    for (int it = 0; it < kIters; ++it) {
        const int sb = it * 16;
        #pragma unroll
        for (int k = 0; k < 16; ++k) {
            const int s = sb + k;

            // ---- sync: up-ready (per 2 steps), down-free (per 8 steps) ----
            if ((k & 1) == 0 && l > 0) {
                while (*upc < s) __builtin_amdgcn_s_sleep(1);
                cbar();
            }
            if ((k == 0 || k == 8) && l < kL - 1) {
                const int need = (k == 0) ? (sb - 8) : sb;
                while (*dnc < need) __builtin_amdgcn_s_sleep(1);
                cbar();
            }

            const int  t      = s - l;
            const bool active = ((unsigned)t < (unsigned)kT);
            const int  rs     = (k + 15) & 15;             // read slot (s-1)

            const f16x8 B1 = *(const f16x8*)(b1b + rs * kSE);
            const f16x8 B2 = *(const f16x8*)(b2b + rs * kSE);

            f32x4 d1 = __builtin_amdgcn_mfma_f32_16x16x32_f16(A2P1, B2, zeroC, 0, 0, 0);
            f32x4 d2 = __builtin_amdgcn_mfma_f32_16x16x32_f16(A2P2, B2, zeroC, 0, 0, 0);
            d1 = __builtin_amdgcn_mfma_f32_16x16x32_f16(A1P1, B1, d1, 0, 0, 0);
            d2 = __builtin_amdgcn_mfma_f32_16x16x32_f16(A1P2, B1, d2, 0, 0, 0);

            float p1s[4], p2s[4];
            #pragma unroll
            for (int r = 0; r < 4; ++r)
                p1s[r] = sigm2(fmaf(-kL2E, d1[r], abk1[r]));
            #pragma unroll
            for (int r = 0; r < 4; ++r)
                p2s[r] = fmaf(am2, sigm2(fmaf(ank2, d2[r], abk2[r])), ams2);

            float hh[2];
            float cc[2] = {c0, c1};
            #pragma unroll
            for (int kk = 0; kk < 2; ++kk) {
                const float T1 = cLow ? p1s[kk + 2] : p1s[kk];
                const float R1 = swz8(T1);
                const float iv = cLow ? p1s[kk] : R1;
                const float fv = cLow ? R1 : p1s[kk + 2];
                const float T2 = cLow ? p2s[kk + 2] : p2s[kk];
                const float R2 = swz8(T2);
                const float gv = cLow ? p2s[kk] : R2;
                const float ov = cLow ? R2 : p2s[kk + 2];

                float cn = fmaf(fv, cc[kk], iv * gv);
                cn = active ? cn : 0.0f;
                cc[kk] = cn;
                const float tc = fmaf(2.0f, sigm2(-2.0f * kL2E * cn), -1.0f);
                hh[kk] = ov * tc;
            }
            c0 = cc[0]; c1 = cc[1];

            f16x2 hp = { (_Float16)hh[0], (_Float16)hh[1] };
            *(f16x2*)(hwb + k * kSE) = hp;                  // h(s) -> slot k

            if (l == 0) {                                   // publish x(s+1)
                _Float16* xw = xwb + k * kSE;
                xw[0] = (_Float16)xg0;
                xw[1] = (_Float16)xg1;
                int tn = s + 2; if (tn > kT - 1) tn = kT - 1;
                float2 v = *(const float2*)(xg_ptr + (size_t)tn * kH);
                xg0 = v.x; xg1 = v.y;
            }

            // ---- release (per 2 steps, lane 0): h(s) committed ----
            if (k & 1) {
                cbar();
                if (lane == 0) *(volatile int*)&cnt[l] = s;
            }
        }
    }

    __syncthreads();

    // ---- head: layer-7 h(T-1) written at s=518 -> slot 518&15 = 6, lyr 8 ----
    if (l == kL - 1) {
        const int bb = lane >> 3;
        const int r  = lane & 7;
        if (r < 6) {
            const bool  isP   = (r < 3);
            const float* wrow = isP ? (Wp + r * kH) : (Wo + (r - 3) * kH);
            float acc = isP ? bpos[r] : bori[r - 3];
            #pragma unroll
            for (int u = 0; u < kH; ++u)
                acc = fmaf((float)hb[6][kL][bb][u], wrow[u], acc);
            if (!isP) acc = fmaf(2.0f, sigm2(-2.0f * kL2E * acc), -1.0f);
            out[(size_t)(blockIdx.x * kNB + bb) * 6 + r] = acc;
        }
    }
}

extern "C" void kernel_launch(void* const* d_in, const int* in_sizes, int n_in,
                              void* d_out, int out_size, void* d_ws, size_t ws_size,
                              hipStream_t stream) {
    const float* x    = (const float*)d_in[0];
    const float* Wih  = (const float*)d_in[1];
    const float* Whh  = (const float*)d_in[2];
    const float* bih  = (const float*)d_in[3];
    const float* bhh  = (const float*)d_in[4];
    const float* Wp   = (const float*)d_in[5];
    const float* bpos = (const float*)d_in[6];
    const float* Wo   = (const float*)d_in[7];
    const float* bori = (const float*)d_in[8];
    float* out = (float*)d_out;

    const int B = in_sizes[0] / (kT * kH);   // 2048
    lstm_async<<<dim3(B / kNB), dim3(512), 0, stream>>>(x, Wih, Whh, bih, bhh,
                                                        Wp, bpos, Wo, bori, out);
}